// Round 16
// baseline (227.113 us; speedup 1.0000x reference)
//
#include <hip/hip_runtime.h>

#define TT 168
#define HH 64
#define DD 7
#define NS 16      // samples per block: ONE N=16 MFMA sample-tile
#define BB 8192
#define CH 8       // timesteps per staged x chunk
#define NTH 1024   // 16 waves: wv 0-7 = L0 engine, wv 8-15 = L1; wave owns 8 units, all 4 gates

typedef float f32x2 __attribute__((ext_vector_type(2)));
typedef float f32x4 __attribute__((ext_vector_type(4)));
typedef _Float16 f16x8 __attribute__((ext_vector_type(8)));

#define MFMA16F(A, B, C) __builtin_amdgcn_mfma_f32_16x16x32_f16((A), (B), (C), 0, 0, 0)

__device__ __forceinline__ f16x8 pack8(f32x4 a, f32x4 b) {
    f16x8 r;
#pragma unroll
    for (int e = 0; e < 4; ++e) { r[e] = (_Float16)a[e]; r[4 + e] = (_Float16)b[e]; }
    return r;
}

__device__ __forceinline__ f32x2 exp2x2(f32x2 a) {
    return (f32x2){__builtin_amdgcn_exp2f(fminf(a.x, 40.0f)),
                   __builtin_amdgcn_exp2f(fminf(a.y, 40.0f))};
}
__device__ __forceinline__ f32x2 rcpx2(f32x2 a) {
    return (f32x2){__builtin_amdgcn_rcpf(a.x), __builtin_amdgcn_rcpf(a.y)};
}

// cell pair (2 units) on packed f32x2 math, PRE-SCALED args (identical to r15):
//   si,sf,so = -log2e*raw; sg = -2log2e*raw; state cs = -2log2e*c
__device__ __forceinline__ void cell_pair(f32x2 si, f32x2 sf, f32x2 sg, f32x2 so,
                                          f32x2& cs, unsigned& dpk) {
    const f32x2 one = {1.0f, 1.0f};
    const f32x2 ui  = exp2x2(si);
    const f32x2 uf  = exp2x2(sf);
    const f32x2 ug  = exp2x2(sg);
    const f32x2 opf = one + uf;
    const f32x2 pig = (one + ui) * (one + ug);
    const f32x2 R1  = rcpx2(pig * opf);
    const f32x2 fv  = pig * R1;
    const f32x2 igs = (ug * 2.88539008f - (f32x2){2.88539008f, 2.88539008f}) * (opf * R1);
    cs = fv * cs + igs;
    const f32x2 uo = exp2x2(so);
    const f32x2 uc = exp2x2(cs);
    const f32x2 R2 = rcpx2((one + uo) * (one + uc));
    const f32x2 hv = (one - uc) * R2;
    asm("v_cvt_pkrtz_f16_f32 %0, %1, %2" : "=v"(dpk) : "v"(hv.x), "v"(hv.y));
}

__global__ __launch_bounds__(NTH, 8)
void weather_lstm_mfma(const float* __restrict__ x,
                       const float* __restrict__ w_ih0, const float* __restrict__ w_hh0,
                       const float* __restrict__ b_ih0, const float* __restrict__ b_hh0,
                       const float* __restrict__ w_ih1, const float* __restrict__ w_hh1,
                       const float* __restrict__ b_ih1, const float* __restrict__ b_hh1,
                       const float* __restrict__ fc_w, const float* __restrict__ fc_b,
                       float* __restrict__ out)
{
    // x frags, ALL 4 k-planes (kg 1..3 stay zero) -> unconditional ds_read_b128
    __shared__ f16x8 xs[2][CH][4][NS];                        // 16 KB
    __shared__ __align__(16) _Float16 h1[2][NS][72];          // 4.6 KB (144B rows)
    __shared__ __align__(16) _Float16 h2[2][NS][72];          // 4.6 KB

    const int tid  = threadIdx.x;
    const int wv   = tid >> 6;       // 0..15
    const int u    = wv & 7;         // unit octet: units 8u..8u+7
    const int lane = tid & 63;
    const int col  = lane & 15;      // A-row within tile / sample
    const int kg   = lane >> 4;      // k-group
    const int s0   = blockIdx.x * NS;
    const int uw   = 8 * u + 2 * kg; // first of the 2 units this lane updates

    // ---------------- init: zero h + ALL x planes ----------------
    for (int i = tid; i < 2 * NS * 72; i += NTH) {
        ((short*)h1)[i] = 0; ((short*)h2)[i] = 0;
    }
    {
        const f16x8 z8i = {0, 0, 0, 0, 0, 0, 0, 0};
        f16x8* xf = &xs[0][0][0][0];
        for (int i = tid; i < 2 * CH * 4 * NS; i += NTH) xf[i] = z8i;
    }
    __syncthreads();
    if (tid < CH * NS) {             // stage chunk 0 into kg=0 plane
        const int tloc = tid >> 4, ss = tid & 15;
        const float* px = x + ((size_t)(s0 + ss) * TT + tloc) * DD;
        f32x4 a, b;
        a[0] = px[0]; a[1] = px[1]; a[2] = px[2]; a[3] = px[3];
        b[0] = px[4]; b[1] = px[5]; b[2] = px[6]; b[3] = 1.0f;   // bias slot
        xs[0][tloc][0][ss] = pack8(a, b);
    }
    __syncthreads();

    const f32x4 zz = {0, 0, 0, 0};

    // Interleaved A-rows: tile t=0 -> gates (i,f), t=1 -> (g,o).
    // A-row col = gate 2t+(col&1), unit 8u+(col>>1).
    // C-row 4kg+e = gate (e&1), unit 8u+2kg+(e>>1) -> lane-local (i,f,g,o) quads.
    if (wv < 8) {
        // ==================== LAYER-0 ENGINE (waves 0-7) ====================
        f16x8 W0[2][2], WX[2];
#pragma unroll
        for (int t = 0; t < 2; ++t) {
            const int gsel = 2 * t + (col & 1);
            const float sc = (gsel == 2) ? -2.88539008f : -1.44269504f;
            const int row = 64 * gsel + 8 * u + (col >> 1);
#pragma unroll
            for (int kf = 0; kf < 2; ++kf) {
                const float* p = w_hh0 + (size_t)row * HH + 32 * kf + 8 * kg;
                W0[t][kf] = pack8(*(const f32x4*)p * sc, *(const f32x4*)(p + 4) * sc);
            }
            f32x4 a = {0, 0, 0, 0}, b = {0, 0, 0, 0};
            if (kg == 0) {
                const float* p = w_ih0 + (size_t)row * DD;
                a[0] = p[0]; a[1] = p[1]; a[2] = p[2]; a[3] = p[3];
                b[0] = p[4]; b[1] = p[5]; b[2] = p[6];
                b[3] = b_ih0[row] + b_hh0[row];     // bias0 rides k-slot 7
            }
            WX[t] = pack8(a * sc, b * sc);
        }
        f32x2 cs = {0, 0};

        const f16x8* xk = &xs[0][0][kg][col];   // step k frag at xk[(k&15)*64]
        const _Float16* r0 = &h1[0][col][8 * kg];            // parity-0 read base
        const _Float16* r1 = r0 + NS * 72;                   // parity-1 (const offset)
        unsigned* wp0 = (unsigned*)&h1[0][col][uw];
        unsigned* wp1 = (unsigned*)((_Float16*)wp0 + NS * 72);

        auto l0_step = [&](int xofs, const _Float16* r, unsigned* wr) {
            const f16x8 ax = xk[xofs];
            f32x4 aP = MFMA16F(WX[0], ax, zz);
            f32x4 aQ = MFMA16F(WX[1], ax, zz);
            f16x8 dh = *(const f16x8*)r;
            aP = MFMA16F(W0[0][0], dh, aP);
            aQ = MFMA16F(W0[1][0], dh, aQ);
            dh = *(const f16x8*)(r + 32);
            aP = MFMA16F(W0[0][1], dh, aP);
            aQ = MFMA16F(W0[1][1], dh, aQ);
            unsigned dpk;
            cell_pair((f32x2){aP[0], aP[2]}, (f32x2){aP[1], aP[3]},
                      (f32x2){aQ[0], aQ[2]}, (f32x2){aQ[1], aQ[3]}, cs, dpk);
            *wr = dpk;
        };
        auto refill = [&](int kref) {          // loads chunk starting at kref+CH
            if (tid < CH * NS) {
                const int tloc = tid >> 4, ss = tid & 15;
                const int tg = kref + CH + tloc;
                const float* px = x + ((size_t)(s0 + ss) * TT + tg) * DD;
                f32x4 a, b;
                a[0] = px[0]; a[1] = px[1]; a[2] = px[2]; a[3] = px[3];
                b[0] = px[4]; b[1] = px[5]; b[2] = px[6]; b[3] = 1.0f;
                const int nb = ((kref >> 3) & 1) ^ 1;
                xs[nb][tloc][0][ss] = pack8(a, b);
            }
        };

        // ---- peel k=0 (reads h1[1]=0, writes h1[0]) and k=1 ----
        refill(0);
        l0_step(0, r1, wp0);
        __syncthreads();
        l0_step(64, r0, wp1);
        __syncthreads();

#pragma unroll 1
        for (int j = 1; j < 84; ++j) {
            const int xofs = ((2 * j) & 15) * 64;
            if ((j & 3) == 0 && j < 80) refill(2 * j);
            l0_step(xofs, r1, wp0);        // k=2j   : read h1[1], write h1[0]
            __syncthreads();
            l0_step(xofs + 64, r0, wp1);   // k=2j+1 : read h1[0], write h1[1]
            __syncthreads();
        }
        __syncthreads();   // epilogue region k=168 (L0 idle)
    } else {
        // ==================== LAYER-1 ENGINE (waves 8-15) ====================
        f16x8 W1[2][4];   // kf 0..1: w_ih1 (h1 input); kf 2..3: w_hh1 (h2 input)
        f32x4 bias1[2];
#pragma unroll
        for (int t = 0; t < 2; ++t) {
            const int gsel = 2 * t + (col & 1);
            const float sc = (gsel == 2) ? -2.88539008f : -1.44269504f;
            const int row = 64 * gsel + 8 * u + (col >> 1);
#pragma unroll
            for (int kf = 0; kf < 4; ++kf) {
                const float* base = (kf < 2) ? (w_ih1 + (size_t)row * HH + 32 * kf)
                                             : (w_hh1 + (size_t)row * HH + 32 * (kf - 2));
                const float* p = base + 8 * kg;
                W1[t][kf] = pack8(*(const f32x4*)p * sc, *(const f32x4*)(p + 4) * sc);
            }
            // bias element e -> C-row 4kg+e: gate 2t+(e&1), unit 8u+2kg+(e>>1)
#pragma unroll
            for (int e = 0; e < 4; ++e) {
                const int g2 = 2 * t + (e & 1);
                const float sce = (g2 == 2) ? -2.88539008f : -1.44269504f;
                const int br = 64 * g2 + 8 * u + 2 * kg + (e >> 1);
                bias1[t][e] = (b_ih1[br] + b_hh1[br]) * sce;
            }
        }
        f32x2 cs = {0, 0};

        const _Float16* p10 = &h1[0][col][8 * kg];
        const _Float16* p11 = p10 + NS * 72;
        const _Float16* p20 = &h2[0][col][8 * kg];
        const _Float16* p21 = p20 + NS * 72;
        unsigned* q0 = (unsigned*)&h2[0][col][uw];
        unsigned* q1 = (unsigned*)((_Float16*)q0 + NS * 72);

        auto l1_step = [&](const _Float16* h1p, const _Float16* h2p, unsigned* wr) {
            f16x8 dh = *(const f16x8*)h1p;
            f32x4 aP = MFMA16F(W1[0][0], dh, bias1[0]);
            f32x4 aQ = MFMA16F(W1[1][0], dh, bias1[1]);
            dh = *(const f16x8*)(h1p + 32);
            aP = MFMA16F(W1[0][1], dh, aP);
            aQ = MFMA16F(W1[1][1], dh, aQ);
            dh = *(const f16x8*)h2p;
            aP = MFMA16F(W1[0][2], dh, aP);
            aQ = MFMA16F(W1[1][2], dh, aQ);
            dh = *(const f16x8*)(h2p + 32);
            aP = MFMA16F(W1[0][3], dh, aP);
            aQ = MFMA16F(W1[1][3], dh, aQ);
            unsigned dpk;
            cell_pair((f32x2){aP[0], aP[2]}, (f32x2){aP[1], aP[3]},
                      (f32x2){aQ[0], aQ[2]}, (f32x2){aQ[1], aQ[3]}, cs, dpk);
            *wr = dpk;
        };

        // ---- peel k=0 (idle) and k=1 (reads h1[0], h2[1]=0, writes h2[0]) ----
        __syncthreads();
        l1_step(p10, p21, q0);
        __syncthreads();

#pragma unroll 1
        for (int j = 1; j < 84; ++j) {
            l1_step(p11, p20, q1);   // k=2j   : cell(k-1) -> h2[1]
            __syncthreads();
            l1_step(p10, p21, q0);   // k=2j+1 : cell(k-1) -> h2[0]
            __syncthreads();
        }
        // ---- epilogue k=168: cell(167) -> h2[1] ----
        l1_step(p11, p20, q1);
        __syncthreads();
    }

    // ---------------- FC head on final h2 = h2(TT-1), slot 1 ----------------
    if (tid < NS * 4) {
        const int s = tid >> 2, k = tid & 3;
        float a = fc_b[k];
#pragma unroll
        for (int j = 0; j < HH; ++j)
            a = fmaf((float)h2[1][s][j], fc_w[k * HH + j], a);
        out[(size_t)(s0 + s) * 4 + k] = a;
    }
}

extern "C" void kernel_launch(void* const* d_in, const int* in_sizes, int n_in,
                              void* d_out, int out_size, void* d_ws, size_t ws_size,
                              hipStream_t stream) {
    const float* x     = (const float*)d_in[0];
    const float* w_ih0 = (const float*)d_in[1];
    const float* w_hh0 = (const float*)d_in[2];
    const float* b_ih0 = (const float*)d_in[3];
    const float* b_hh0 = (const float*)d_in[4];
    const float* w_ih1 = (const float*)d_in[5];
    const float* w_hh1 = (const float*)d_in[6];
    const float* b_ih1 = (const float*)d_in[7];
    const float* b_hh1 = (const float*)d_in[8];
    const float* fc_w  = (const float*)d_in[9];
    const float* fc_b  = (const float*)d_in[10];
    float* out = (float*)d_out;

    dim3 grid(BB / NS), block(NTH);
    weather_lstm_mfma<<<grid, block, 0, stream>>>(
        x, w_ih0, w_hh0, b_ih0, b_hh0,
        w_ih1, w_hh1, b_ih1, b_hh1, fc_w, fc_b, out);
}